// Round 7
// baseline (157.499 us; speedup 1.0000x reference)
//
#include <hip/hip_runtime.h>
#include <math.h>

// Problem constants (fixed by setup_inputs)
#define N_TOTAL 2097152
#define NT 256
// pass1 geometry: per-wave window of 512 elems = 64 lanes x 8;
// lanes 0..31 = warmup (256 elems), lanes 32..63 own 256 elems.
#define NC1 8
#define OWN_W 256
#define OWN_B 1024
#define NB1 (N_TOTAL / OWN_B)        // 2048 blocks
// pass2 geometry: 4 elems/thread
#define NC2 4
#define NB2 (N_TOTAL / (NT * NC2))   // 2048 blocks
#define NWAVES 4

// ---- fp64 2x2 Moebius for the x (Riccati) state -------------------------
// x' = (al*x + be)/(ga*x + de). Elem: al=p(dg-s2u2), be=u^2, ga=-p*U^2,
// de=dg+s2u2; det = p*dg^2 > 0 exactly. Windows are <=512 elements: the
// contraction (~e^-0.035/elem) means 256-elem warmup reproduces x to <1e-4.
// COMPOSITION MUST BE fp64: window det ratio ~1e-9 vs fp32 eps 1e-7 (NaN'd
// in rounds 1,2,6); fp64 eps 1e-16 gives 1e7x headroom (proven round 3+).
struct DM2 { double al, be, ga, de; };
struct Aff { float A, B; };   // g' = A*g + B (affine, perfectly conditioned)

__device__ __forceinline__ DM2 dm2_id() { DM2 m; m.al=1.0; m.be=0.0; m.ga=0.0; m.de=1.0; return m; }
__device__ __forceinline__ DM2 dm2_compose(const DM2& A, const DM2& B) {  // A after B
    DM2 r;
    r.al = A.al*B.al + A.be*B.ga;
    r.be = A.al*B.be + A.be*B.de;
    r.ga = A.ga*B.al + A.de*B.ga;
    r.de = A.ga*B.be + A.de*B.de;
    return r;
}
__device__ __forceinline__ void dm2_norm(DM2& m) {
    double mx = fmax(fmax(fabs(m.al), fabs(m.be)), fmax(fabs(m.ga), fabs(m.de)));
    if (!(mx > 0.0) || isinf(mx)) return;
    double inv = 1.0 / mx;
    m.al *= inv; m.be *= inv; m.ga *= inv; m.de *= inv;
}
__device__ __forceinline__ DM2 dm2_shfl_up(const DM2& m, int d) {
    DM2 r;
    r.al = __shfl_up(m.al, d, 64);
    r.be = __shfl_up(m.be, d, 64);
    r.ga = __shfl_up(m.ga, d, 64);
    r.de = __shfl_up(m.de, d, 64);
    return r;
}
__device__ __forceinline__ Aff aff_id() { Aff a; a.A=1.f; a.B=0.f; return a; }
__device__ __forceinline__ Aff aff_compose(const Aff& L, const Aff& E) { // later∘earlier
    Aff r; r.A = L.A*E.A; r.B = L.A*E.B + L.B; return r;
}
__device__ __forceinline__ Aff aff_shfl_up(const Aff& a, int d) {
    Aff r; r.A = __shfl_up(a.A, d, 64); r.B = __shfl_up(a.B, d, 64); return r;
}
__device__ __forceinline__ Aff aff_wave_scan(Aff mine, int lane) { // inclusive, ordered
    #pragma unroll
    for (int d = 1; d < 64; d <<= 1) {
        Aff o = aff_shfl_up(mine, d);
        if (lane >= d) mine = aff_compose(mine, o);
    }
    return mine;
}

// ------ Kernel 1: windowed-x (fp64 M2) -> logD, block affine, packed ------
__global__ __launch_bounds__(NT, 4) void k_pass1(
    const float* __restrict__ t, const int* __restrict__ band,
    const float* __restrict__ y, const float* __restrict__ yerr,
    const float* __restrict__ lad, const float* __restrict__ lkp,
    float4* __restrict__ packed, float2* __restrict__ baff,
    float* __restrict__ blogd)
{
    __shared__ float2 smaff[NWAVES];
    __shared__ float  smlog[NWAVES];
    const int tid = threadIdx.x, lane = tid & 63, wv = tid >> 6;
    const float sigma2 = __expf(2.f * lkp[0]);
    const float inv_ell = __expf(-lkp[1]);
    float amps[4] = {1.f, __expf(lad[0]), __expf(lad[1]), __expf(lad[2])};

    const int own0 = blockIdx.x * OWN_B + wv * OWN_W;
    const int base = own0 - OWN_W + lane * NC1;  // window [own0-256, own0+256)
    const bool valid = (base >= 0);  // false only: block 0, wave 0, lanes<32

    float Pv[NC1], dgv[NC1], uv[NC1], yv[NC1];
    DM2 acc = dm2_id();
    if (valid) {
        float tprev = (base == 0) ? 0.f : t[base - 1];
        #pragma unroll
        for (int k = 0; k < NC1; k += 4) {
            float4 tv  = *reinterpret_cast<const float4*>(t + base + k);
            float4 yv4 = *reinterpret_cast<const float4*>(y + base + k);
            float4 ev  = *reinterpret_cast<const float4*>(yerr + base + k);
            int4   bv  = *reinterpret_cast<const int4*>(band + base + k);
            float tc[4] = {tv.x, tv.y, tv.z, tv.w};
            float yc[4] = {yv4.x, yv4.y, yv4.z, yv4.w};
            float ec[4] = {ev.x, ev.y, ev.z, ev.w};
            int   bc[4] = {bv.x, bv.y, bv.z, bv.w};
            #pragma unroll
            for (int j = 0; j < 4; ++j) {
                float u = amps[bc[j] & 3];
                float dg = ec[j] * ec[j];
                float s2u2 = sigma2 * u * u;
                float P = ((base + k + j) == 0) ? 0.f
                        : __expf(-(tc[j] - tprev) * inv_ell);
                float U = sigma2 * u;
                float p = P * P;
                DM2 e;
                e.al = (double)(p * (dg - s2u2));
                e.be = (double)(u * u);
                e.ga = -(double)(p * U * U);
                e.de = (double)(dg + s2u2);
                acc = dm2_compose(e, acc);  // 8-chain: entries bounded, no norm
                Pv[k+j] = P; dgv[k+j] = dg; uv[k+j] = u; yv[k+j] = yc[j];
                tprev = tc[j];
            }
        }
        dm2_norm(acc);
    }
    // fp64 Kogge-Stone over the 64-lane window
    DM2 incl = acc;
    #pragma unroll
    for (int d = 1; d < 64; d <<= 1) {
        DM2 o = dm2_shfl_up(incl, d);
        if (lane >= d) { incl = dm2_compose(incl, o); dm2_norm(incl); }
    }
    DM2 lex = dm2_shfl_up(incl, 1);
    if (lane == 0) lex = dm2_id();
    // x from exclusive composite applied at 0 (well-conditioned point)
    float x = 0.f;
    if (lex.de != 0.0) {
        double xx = lex.be / lex.de;
        if (isfinite(xx)) x = (float)xx;
    }
    x = fminf(fmaxf(x, 0.f), 4.f);   // true x in [0, ~1.3]; clamp = inf-guard

    float slog = 0.f;
    Aff a = aff_id();
    if (lane >= 32) {   // owned lanes
        #pragma unroll
        for (int k = 0; k < NC1; ++k) {
            float P = Pv[k], dg = dgv[k], u = uv[k], yy = yv[k];
            float U = sigma2 * u;
            float av = dg + U * u;
            float p = P * P;
            float S = p * x;
            float D = av - U * U * S;
            if (!(D > 1e-4f)) D = 1e-4f;   // true D >= dg >= 0.01
            float iD = 1.f / D;
            float W = (u - S * U) * iD;
            slog += __logf(D);
            float rs = sqrtf(iD);
            float c1 = U * P;
            float rho = P - c1 * W;         // P*(1 - W*U), in (0,1)
            float Wy = W * yy;
            float4 pk; pk.x = rho; pk.y = Wy; pk.z = yy * rs; pk.w = c1 * rs;
            packed[base + k] = pk;
            a.B = rho * a.B + Wy;
            a.A *= rho;
            x = S + D * W * W;
        }
    }
    Aff ai = aff_wave_scan(a, lane);        // warmup lanes hold identity
    #pragma unroll
    for (int d = 32; d > 0; d >>= 1) slog += __shfl_down(slog, d, 64);
    if (lane == 63) { float2 v; v.x = ai.A; v.y = ai.B; smaff[wv] = v; }
    if (lane == 0) smlog[wv] = slog;
    __syncthreads();
    if (tid == 0) {
        Aff bacc; bacc.A = smaff[0].x; bacc.B = smaff[0].y;
        #pragma unroll
        for (int w = 1; w < NWAVES; ++w) {
            Aff ww; ww.A = smaff[w].x; ww.B = smaff[w].y;
            bacc = aff_compose(ww, bacc);
        }
        float2 ov; ov.x = bacc.A; ov.y = bacc.B;
        baff[blockIdx.x] = ov;
        blogd[blockIdx.x] = smlog[0] + smlog[1] + smlog[2] + smlog[3];
    }
}

// ---- Kernel 2: affine spine over 2048 blocks; logD total; zero accum -----
__global__ __launch_bounds__(NT) void k_spine(
    const float2* __restrict__ baff, const float* __restrict__ blogd,
    float* __restrict__ gstart, double* __restrict__ accum,
    unsigned int* __restrict__ counter)
{
    __shared__ float2 smw[NWAVES];
    __shared__ double smd[NWAVES];
    const int tid = threadIdx.x, lane = tid & 63, wv = tid >> 6;
    Aff m[8];
    double ld = 0.0;
    #pragma unroll
    for (int j = 0; j < 8; ++j) {
        float2 v = baff[8 * tid + j];
        m[j].A = v.x; m[j].B = v.y;
        ld += (double)blogd[8 * tid + j];
    }
    Aff acc = m[0];
    #pragma unroll
    for (int j = 1; j < 8; ++j) acc = aff_compose(m[j], acc);
    Aff incl = aff_wave_scan(acc, lane);
    #pragma unroll
    for (int d = 32; d > 0; d >>= 1) ld += __shfl_down(ld, d, 64);
    if (lane == 63) { float2 v; v.x = incl.A; v.y = incl.B; smw[wv] = v; }
    if (lane == 0) smd[wv] = ld;
    __syncthreads();
    Aff wpre = aff_id();
    for (int w = 0; w < wv; ++w) {          // wave-uniform, <=3 composes
        Aff ww; ww.A = smw[w].x; ww.B = smw[w].y;
        wpre = aff_compose(ww, wpre);
    }
    Aff lex = aff_shfl_up(incl, 1);
    if (lane == 0) lex = aff_id();
    Aff tex = aff_compose(lex, wpre);       // exclusive over blocks [0, 8*tid)
    #pragma unroll
    for (int j = 0; j < 8; ++j) {
        gstart[8 * tid + j] = tex.B;        // g0 = 0 -> g at block start = B
        tex = aff_compose(m[j], tex);
    }
    if (tid == 0) {
        accum[0] = smd[0] + smd[1] + smd[2] + smd[3];
        accum[1] = 0.0;
        *counter = 0u;
    }
}

// ------- Kernel 3: g replay from packed float4 -> quad + finalize ---------
__global__ __launch_bounds__(NT, 4) void k_pass2(
    const float4* __restrict__ packed, const float* __restrict__ gstart,
    double* __restrict__ accum, unsigned int* __restrict__ counter,
    float* __restrict__ out)
{
    __shared__ float2 smaff[NWAVES];
    __shared__ float  smq[NWAVES];
    const int tid = threadIdx.x, lane = tid & 63, wv = tid >> 6;
    const int base = blockIdx.x * (NT * NC2) + tid * NC2;
    float4 pk[NC2];
    #pragma unroll
    for (int k = 0; k < NC2; ++k) pk[k] = packed[base + k];

    Aff a = aff_id();
    #pragma unroll
    for (int k = 0; k < NC2; ++k) {
        a.B = pk[k].x * a.B + pk[k].y;
        a.A *= pk[k].x;
    }
    Aff incl = aff_wave_scan(a, lane);
    Aff lex = aff_shfl_up(incl, 1);
    if (lane == 0) lex = aff_id();
    if (lane == 63) { float2 v; v.x = incl.A; v.y = incl.B; smaff[wv] = v; }
    __syncthreads();
    Aff wpre = aff_id();
    for (int w = 0; w < wv; ++w) {
        Aff ww; ww.A = smaff[w].x; ww.B = smaff[w].y;
        wpre = aff_compose(ww, wpre);
    }
    Aff te = aff_compose(lex, wpre);        // exclusive within block
    float gblk = gstart[blockIdx.x];
    if (!isfinite(gblk)) gblk = 0.f;
    float g = te.A * gblk + te.B;
    if (!isfinite(g)) g = 0.f;

    float q = 0.f;
    #pragma unroll
    for (int k = 0; k < NC2; ++k) {
        float z = pk[k].z - pk[k].w * g;    // (y - c1*g)/sqrt(D)
        q += z * z;
        g = pk[k].x * g + pk[k].y;          // g' = rho*g + W*y
    }
    #pragma unroll
    for (int d = 32; d > 0; d >>= 1) q += __shfl_down(q, d, 64);
    if (lane == 0) smq[wv] = q;
    __syncthreads();
    if (tid == 0) {
        double qt = (double)smq[0] + (double)smq[1]
                  + (double)smq[2] + (double)smq[3];
        atomicAdd(&accum[1], qt);
        __threadfence();
        unsigned int old = atomicAdd(counter, 1u);
        if (old == NB2 - 1) {   // last block: finalize
            double s0 = atomicAdd(&accum[0], 0.0);   // logD (from spine)
            double s1 = atomicAdd(&accum[1], 0.0);   // quad
            double r = -0.5 * (s0 + s1
                       + (double)N_TOTAL * 1.8378770664093454836);  // log(2pi)
            out[0] = (float)r;
        }
    }
}

extern "C" void kernel_launch(void* const* d_in, const int* in_sizes, int n_in,
                              void* d_out, int out_size, void* d_ws, size_t ws_size,
                              hipStream_t stream)
{
    const float* t    = (const float*)d_in[0];
    const int*   band = (const int*)d_in[1];
    const float* y    = (const float*)d_in[2];
    const float* yerr = (const float*)d_in[3];
    const float* lad  = (const float*)d_in[4];
    const float* lkp  = (const float*)d_in[5];

    char* ws = (char*)d_ws;
    float4* packed = (float4*)ws;                             // N * 16 B
    size_t off = (size_t)N_TOTAL * 16;
    float2* baff   = (float2*)(ws + off);   off += NB1 * 8;   // 16 KB
    float*  blogd  = (float*)(ws + off);    off += NB1 * 4;   // 8 KB
    float*  gstart = (float*)(ws + off);    off += NB1 * 4;   // 8 KB
    double* accum  = (double*)(ws + off);   off += 16;
    unsigned int* counter = (unsigned int*)(ws + off);

    k_pass1<<<NB1, NT, 0, stream>>>(t, band, y, yerr, lad, lkp,
                                    packed, baff, blogd);
    k_spine<<<1, NT, 0, stream>>>(baff, blogd, gstart, accum, counter);
    k_pass2<<<NB2, NT, 0, stream>>>(packed, gstart, accum, counter,
                                    (float*)d_out);
}